// Round 11
// baseline (199.038 us; speedup 1.0000x reference)
//
#include <hip/hip_runtime.h>
#include <math.h>

// B=32, HID=4096, NH=32, NKV=8, HS=128, BS=16, MAXS=2048, groups=4

// ---------------------------------------------------------------------------
// Split-K f32 GEMM v1 (known-good). out[b][n] += x[b][:] . w[n][:].
// BM=32, BN=256, BK=32. 256 threads, 32 accumulators/thread.
// ---------------------------------------------------------------------------
__device__ __forceinline__ void gemm_body(
    const float* __restrict__ x, const float* __restrict__ w,
    float* __restrict__ dst, int dstride, int kbase, int kcnt)
{
    __shared__ float xs[32][36];
    __shared__ float wsm[32][257];   // [k][n]
    int t = threadIdx.x;
    float acc[4][8];
#pragma unroll
    for (int i = 0; i < 4; ++i)
#pragma unroll
        for (int j = 0; j < 8; ++j) acc[i][j] = 0.f;

    int nsub = t & 31, bsub = t >> 5;

    for (int kt = 0; kt < kcnt; kt += 32) {
        int k0 = kbase + kt;
        {
            int b = t >> 3, k4 = (t & 7) << 2;
            float4 xv = *(const float4*)(x + (size_t)b * 4096 + k0 + k4);
            *(float4*)&xs[b][k4] = xv;
        }
        {
            int k4 = (t & 7) << 2;
            int nl0 = t >> 3;
#pragma unroll
            for (int i = 0; i < 8; ++i) {
                int nl = nl0 + (i << 5);
                float4 wv = *(const float4*)(w + (size_t)nl * 4096 + k0 + k4);
                wsm[k4 + 0][nl] = wv.x;
                wsm[k4 + 1][nl] = wv.y;
                wsm[k4 + 2][nl] = wv.z;
                wsm[k4 + 3][nl] = wv.w;
            }
        }
        __syncthreads();
#pragma unroll
        for (int k = 0; k < 32; ++k) {
            float xv[4], wv[8];
#pragma unroll
            for (int j = 0; j < 4; ++j) xv[j] = xs[bsub * 4 + j][k];
#pragma unroll
            for (int j = 0; j < 8; ++j) wv[j] = wsm[k][nsub + (j << 5)];
#pragma unroll
            for (int jb = 0; jb < 4; ++jb)
#pragma unroll
                for (int jn = 0; jn < 8; ++jn)
                    acc[jb][jn] = fmaf(xv[jb], wv[jn], acc[jb][jn]);
        }
        __syncthreads();
    }
#pragma unroll
    for (int jb = 0; jb < 4; ++jb) {
        int b = bsub * 4 + jb;
#pragma unroll
        for (int jn = 0; jn < 8; ++jn)
            atomicAdd(dst + (size_t)b * dstride + nsub + (jn << 5), acc[jb][jn]);
    }
}

// grid = 24 tiles * 16 splits
__global__ __launch_bounds__(256) void qkv_gemm(
    const float* __restrict__ x, const float* __restrict__ wq,
    const float* __restrict__ wk, const float* __restrict__ wv,
    float* __restrict__ qb, float* __restrict__ knb, float* __restrict__ vnb)
{
    int split = blockIdx.x & 15;
    int tile  = blockIdx.x >> 4;
    const float* w; float* dst; int dstride;
    if (tile < 16)      { w = wq + (size_t)tile * 256 * 4096;        dst = qb  + tile * 256;        dstride = 4096; }
    else if (tile < 20) { w = wk + (size_t)(tile - 16) * 256 * 4096; dst = knb + (tile - 16) * 256; dstride = 1024; }
    else                { w = wv + (size_t)(tile - 20) * 256 * 4096; dst = vnb + (tile - 20) * 256; dstride = 1024; }
    gemm_body(x, w, dst, dstride, split * 256, 256);
}

// grid = 16 tiles * 16 splits
__global__ __launch_bounds__(256) void wo_gemm(
    const float* __restrict__ attn, const float* __restrict__ wo,
    float* __restrict__ out)
{
    int split = blockIdx.x & 15;
    int tile  = blockIdx.x >> 4;
    gemm_body(attn, wo + (size_t)tile * 256 * 4096, out + tile * 256, 4096, split * 256, 256);
}

// ---------------------------------------------------------------------------
// RoPE in-place on q (32 heads) and k_new (8 heads). grid = 32*40, block = 64.
// ---------------------------------------------------------------------------
__global__ void rope_kernel(float* __restrict__ qb, float* __restrict__ knb,
                            const int* __restrict__ lens)
{
    int bid = blockIdx.x;
    int b = bid / 40, r = bid % 40;
    float* row = (r < 32) ? (qb + (size_t)b * 4096 + r * 128)
                          : (knb + (size_t)b * 1024 + (r - 32) * 128);
    int d = threadIdx.x;
    float pos = (float)(lens[b] - 1);
    float inv = exp2f(-(float)d * 0.207620505930460f);  // 10000^(-d/64)
    float fr = pos * inv;
    float s, c;
    sincosf(fr, &s, &c);
    float x1 = row[d], x2 = row[d + 64];
    row[d]      = x1 * c - x2 * s;
    row[d + 64] = x2 * c + x1 * s;
}

// ---------------------------------------------------------------------------
// Flash-decode attention v4: FULL-ROW STREAMING. One wave per (b, 32-pos
// chunk); no kv-head dimension in the grid. Per position (round) the 64 lanes
// read the ENTIRE 4KB K row + 4KB V row (lane offset = lane*64B, dense
// contiguous stream; every KV byte read exactly once by exactly one wave).
// Lane = (h = lane>>3 kv-head, i = lane&7 -> 16-float dim slice). Each lane
// computes 4 GQA q-head dots over its slice (16 FMA each), 8-lane RED8
// (3 shuffles), subgroup-local online softmax (no cross-group merges ever),
// PV into 4x16 accumulator floats. 2-deep named-reg prefetch, zero barriers,
// zero LDS. Block order bid = c*32+b puts chunk idx in HIGH bits: a CU's
// resident blocks (stride 256) span all c values -> uniform activity per CU
// (v2/v3 had bid=b*128+h*16+c -> each CU stuck with ONE c -> the c=0 CUs did
// ~90% of the work while c=15 CUs idled; why all per-wave tuning was null).
// ---------------------------------------------------------------------------
#define V4MUL(V, S) { V.x *= S; V.y *= S; V.z *= S; V.w *= S; }
#define V4FMA(O, P, V) { O.x = fmaf(P, V.x, O.x); O.y = fmaf(P, V.y, O.y); \
                         O.z = fmaf(P, V.z, O.z); O.w = fmaf(P, V.w, O.w); }
#define DOT4(S, Q, K) { S = fmaf(Q.x, K.x, S); S = fmaf(Q.y, K.y, S); \
                        S = fmaf(Q.z, K.z, S); S = fmaf(Q.w, K.w, S); }
#define RED8(X) { X += __shfl_xor(X, 1, 64); X += __shfl_xor(X, 2, 64); \
                  X += __shfl_xor(X, 4, 64); }

// load round r_'s full-row slice (16 K floats + 16 V floats) into set S
#define LOADR(S, r_) { \
    int p_ = p0 + (r_); \
    const float* kp_; const float* vp_; \
    if (p_ == last) { kp_ = knew; vp_ = vnew; } \
    else { \
        int sl_ = ((r_) < 16) ? (bt0x16 + (r_)) : (bt1x16 + (r_) - 16); \
        kp_ = kc + (size_t)sl_ * 1024 + l16; \
        vp_ = vc + (size_t)sl_ * 1024 + l16; \
    } \
    S##k0 = *(const float4*)(kp_);      S##k1 = *(const float4*)(kp_ + 4); \
    S##k2 = *(const float4*)(kp_ + 8);  S##k3 = *(const float4*)(kp_ + 12); \
    S##v0 = *(const float4*)(vp_);      S##v1 = *(const float4*)(vp_ + 4); \
    S##v2 = *(const float4*)(vp_ + 8);  S##v3 = *(const float4*)(vp_ + 12); }

// online update for q-head g from score s_ and V slice of set S
#define OUPD(S, s_, m_, l_, O0_, O1_, O2_, O3_) { \
    if (s_ > m_) { \
        float c_ = __expf(m_ - s_); \
        l_ *= c_; V4MUL(O0_, c_) V4MUL(O1_, c_) V4MUL(O2_, c_) V4MUL(O3_, c_) \
        m_ = s_; \
    } \
    float pe_ = __expf(s_ - m_); \
    l_ += pe_; \
    V4FMA(O0_, pe_, S##v0) V4FMA(O1_, pe_, S##v1) \
    V4FMA(O2_, pe_, S##v2) V4FMA(O3_, pe_, S##v3) }

#define COMP(S, r_) { \
    float s0 = 0.f, s1 = 0.f, s2 = 0.f, s3 = 0.f; \
    DOT4(s0, q00, S##k0) DOT4(s0, q01, S##k1) DOT4(s0, q02, S##k2) DOT4(s0, q03, S##k3) \
    DOT4(s1, q10, S##k0) DOT4(s1, q11, S##k1) DOT4(s1, q12, S##k2) DOT4(s1, q13, S##k3) \
    DOT4(s2, q20, S##k0) DOT4(s2, q21, S##k1) DOT4(s2, q22, S##k2) DOT4(s2, q23, S##k3) \
    DOT4(s3, q30, S##k0) DOT4(s3, q31, S##k1) DOT4(s3, q32, S##k2) DOT4(s3, q33, S##k3) \
    RED8(s0) RED8(s1) RED8(s2) RED8(s3) \
    OUPD(S, s0, m0, l0, o00, o01, o02, o03) \
    OUPD(S, s1, m1, l1, o10, o11, o12, o13) \
    OUPD(S, s2, m2, l2, o20, o21, o22, o23) \
    OUPD(S, s3, m3, l3, o30, o31, o32, o33) }

__global__ __launch_bounds__(64, 1) void attn_kernel(
    const float* __restrict__ kc, const float* __restrict__ vc,
    const float* __restrict__ qb, const float* __restrict__ knb,
    const float* __restrict__ vnb,
    const int* __restrict__ btab, const int* __restrict__ lens,
    float* __restrict__ part)
{
    int bid = blockIdx.x;
    int c = bid >> 5, b = bid & 31;     // chunk-major: CU stride 256 spans c
    int len = lens[b];
    int p0 = c << 5;
    if (p0 >= len) return;
    int pend = min(len - p0, 32);
    int last = len - 1;

    int lane = threadIdx.x;
    int h = lane >> 3;            // kv-head 0..7
    int i = lane & 7;             // dim slice (16 floats)
    int l16 = lane << 4;          // full-row lane offset (lane*64B)

    int bt0x16 = btab[b * 128 + (p0 >> 4)] << 4;
    int bt1x16 = btab[b * 128 + (p0 >> 4) + 1] << 4;

    const float* knew = knb + (size_t)b * 1024 + l16;
    const float* vnew = vnb + (size_t)b * 1024 + l16;

    // q slices for the 4 GQA heads of this lane's kv-head, prescaled
    const float scale = 0.08838834764831845f;   // 1/sqrt(128)
    const float* qr = qb + (size_t)b * 4096 + (size_t)h * 512 + (i << 4);
    float4 q00 = *(const float4*)(qr),        q01 = *(const float4*)(qr + 4);
    float4 q02 = *(const float4*)(qr + 8),    q03 = *(const float4*)(qr + 12);
    float4 q10 = *(const float4*)(qr + 128),  q11 = *(const float4*)(qr + 132);
    float4 q12 = *(const float4*)(qr + 136),  q13 = *(const float4*)(qr + 140);
    float4 q20 = *(const float4*)(qr + 256),  q21 = *(const float4*)(qr + 260);
    float4 q22 = *(const float4*)(qr + 264),  q23 = *(const float4*)(qr + 268);
    float4 q30 = *(const float4*)(qr + 384),  q31 = *(const float4*)(qr + 388);
    float4 q32 = *(const float4*)(qr + 392),  q33 = *(const float4*)(qr + 396);
    V4MUL(q00, scale) V4MUL(q01, scale) V4MUL(q02, scale) V4MUL(q03, scale)
    V4MUL(q10, scale) V4MUL(q11, scale) V4MUL(q12, scale) V4MUL(q13, scale)
    V4MUL(q20, scale) V4MUL(q21, scale) V4MUL(q22, scale) V4MUL(q23, scale)
    V4MUL(q30, scale) V4MUL(q31, scale) V4MUL(q32, scale) V4MUL(q33, scale)

    float m0 = -INFINITY, m1 = -INFINITY, m2 = -INFINITY, m3 = -INFINITY;
    float l0 = 0.f, l1 = 0.f, l2 = 0.f, l3 = 0.f;
    float4 o00 = {0,0,0,0}, o01 = {0,0,0,0}, o02 = {0,0,0,0}, o03 = {0,0,0,0};
    float4 o10 = {0,0,0,0}, o11 = {0,0,0,0}, o12 = {0,0,0,0}, o13 = {0,0,0,0};
    float4 o20 = {0,0,0,0}, o21 = {0,0,0,0}, o22 = {0,0,0,0}, o23 = {0,0,0,0};
    float4 o30 = {0,0,0,0}, o31 = {0,0,0,0}, o32 = {0,0,0,0}, o33 = {0,0,0,0};

    float4 ak0, ak1, ak2, ak3, av0, av1, av2, av3;
    float4 bk0, bk1, bk2, bk3, bv0, bv1, bv2, bv3;

    LOADR(a, 0)
    if (1 < pend) LOADR(b, 1)
    for (int r = 0; r < pend; r += 2) {
        COMP(a, r)
        if (r + 2 < pend) LOADR(a, r + 2)
        if (r + 1 >= pend) break;
        COMP(b, r + 1)
        if (r + 3 < pend) LOADR(b, r + 3)
    }

    // write partials: per (b,c): 32 q-heads x 132 floats [O[128], m, l, pad2]
    float* pgb = part + (size_t)(b * 64 + c) * 4224;
    int i16 = i << 4;
    float* d0 = pgb + (size_t)(h * 4 + 0) * 132 + i16;
    float* d1 = pgb + (size_t)(h * 4 + 1) * 132 + i16;
    float* d2 = pgb + (size_t)(h * 4 + 2) * 132 + i16;
    float* d3 = pgb + (size_t)(h * 4 + 3) * 132 + i16;
    *(float4*)(d0) = o00; *(float4*)(d0 + 4) = o01; *(float4*)(d0 + 8) = o02; *(float4*)(d0 + 12) = o03;
    *(float4*)(d1) = o10; *(float4*)(d1 + 4) = o11; *(float4*)(d1 + 8) = o12; *(float4*)(d1 + 12) = o13;
    *(float4*)(d2) = o20; *(float4*)(d2 + 4) = o21; *(float4*)(d2 + 8) = o22; *(float4*)(d2 + 12) = o23;
    *(float4*)(d3) = o30; *(float4*)(d3 + 4) = o31; *(float4*)(d3 + 8) = o32; *(float4*)(d3 + 12) = o33;
    if (i == 0) {
        pgb[(h * 4 + 0) * 132 + 128] = m0; pgb[(h * 4 + 0) * 132 + 129] = l0;
        pgb[(h * 4 + 1) * 132 + 128] = m1; pgb[(h * 4 + 1) * 132 + 129] = l1;
        pgb[(h * 4 + 2) * 132 + 128] = m2; pgb[(h * 4 + 2) * 132 + 129] = l2;
        pgb[(h * 4 + 3) * 132 + 128] = m3; pgb[(h * 4 + 3) * 132 + 129] = l3;
    }
}

// grid = 256 (b*8+h), block = 256 (4 q-heads x 64 lanes)
__global__ __launch_bounds__(256) void combine_kernel(
    const float* __restrict__ part, const int* __restrict__ lens,
    float* __restrict__ attn)
{
    int b = blockIdx.x >> 3, h = blockIdx.x & 7;
    int t = threadIdx.x;
    int g = t >> 6, lane = t & 63;
    int len = lens[b];
    int nch = (len + 31) >> 5;          // up to 64 chunks
    const float* base = part + (size_t)b * 64 * 4224 + (size_t)(h * 4 + g) * 132;
    float M = -INFINITY;
    for (int cc = 0; cc < nch; ++cc)
        M = fmaxf(M, base[(size_t)cc * 4224 + 128]);
    float denom = 0.f, a0 = 0.f, a1 = 0.f;
    int d0 = lane << 1;
    for (int cc = 0; cc < nch; ++cc) {
        const float* pg = base + (size_t)cc * 4224;
        float w = __expf(pg[128] - M);
        denom += w * pg[129];
        a0 += w * pg[d0];
        a1 += w * pg[d0 + 1];
    }
    float inv = 1.f / denom;
    float* dst = attn + (size_t)b * 4096 + (size_t)(h * 4 + g) * 128 + d0;
    dst[0] = a0 * inv;
    dst[1] = a1 * inv;
}

// ---------------------------------------------------------------------------
// Workspace (floats): qb[32][4096] @0, knb[32*1024] @131072, vnb @163840,
// attn[32][4096] @196608, part[32*64*4224] @327680 (~35MB; ws is 1GiB)
// ---------------------------------------------------------------------------
extern "C" void kernel_launch(void* const* d_in, const int* in_sizes, int n_in,
                              void* d_out, int out_size, void* d_ws, size_t ws_size,
                              hipStream_t stream)
{
    const float* x   = (const float*)d_in[0];
    const float* wq  = (const float*)d_in[1];
    const float* wk  = (const float*)d_in[2];
    const float* wv  = (const float*)d_in[3];
    const float* wo  = (const float*)d_in[4];
    const float* kc  = (const float*)d_in[5];
    const float* vc  = (const float*)d_in[6];
    const int* btab  = (const int*)d_in[8];
    const int* lens  = (const int*)d_in[10];

    float* qb   = (float*)d_ws;
    float* knb  = qb  + 32 * 4096;
    float* vnb  = knb + 32 * 1024;
    float* attn = vnb + 32 * 1024;
    float* part = attn + 32 * 4096;
    float* outp = (float*)d_out;

    hipMemsetAsync(d_ws, 0, (size_t)(32 * 4096 + 2 * 32 * 1024) * sizeof(float), stream);
    hipMemsetAsync(d_out, 0, (size_t)32 * 4096 * sizeof(float), stream);

    qkv_gemm<<<24 * 16, 256, 0, stream>>>(x, wq, wk, wv, qb, knb, vnb);
    rope_kernel<<<32 * 40, 64, 0, stream>>>(qb, knb, lens);
    attn_kernel<<<2048, 64, 0, stream>>>(kc, vc, qb, knb, vnb, btab, lens, part);
    combine_kernel<<<256, 256, 0, stream>>>(part, lens, attn);
    wo_gemm<<<16 * 16, 256, 0, stream>>>(attn, wo, outp);
}

// Round 12
// 181.534 us; speedup vs baseline: 1.0964x; 1.0964x over previous
//
#include <hip/hip_runtime.h>
#include <math.h>

// B=32, HID=4096, NH=32, NKV=8, HS=128, BS=16, MAXS=2048, groups=4

typedef __attribute__((ext_vector_type(8))) short bf16x8;
typedef __attribute__((ext_vector_type(4))) float f32x4;

// ---------------------------------------------------------------------------
// bf16 MFMA GEMM (replaces LDS-issue-bound f32 v1; R6 showed GEMMs are a
// >=50us lever). One wave per (16x16 C-tile, K=1024 split): A-frag = 8
// contiguous K-floats of x[m0+(lane&15)], B-frag = 8 contiguous K-floats of
// w[n0+(lane&15)] (B[k][n]=w[n][k] -> same load shape). Any consistent
// k-permutation inside the frag cancels between A and B. C/D mapping
// (m89-verified): col=lane&15, row=(lane>>4)*4+j. f32 atomicAdd merges the 4
// K-splits. No LDS, no barriers; 12 waves/CU stream weights once.
// ---------------------------------------------------------------------------
__device__ __forceinline__ unsigned short f2bf(float f) {
    unsigned int u = __float_as_uint(f);
    return (unsigned short)((u + 0x7FFFu + ((u >> 16) & 1u)) >> 16);
}
__device__ __forceinline__ bf16x8 cvt8(float4 a, float4 b) {
    bf16x8 r;
    r[0] = (short)f2bf(a.x); r[1] = (short)f2bf(a.y);
    r[2] = (short)f2bf(a.z); r[3] = (short)f2bf(a.w);
    r[4] = (short)f2bf(b.x); r[5] = (short)f2bf(b.y);
    r[6] = (short)f2bf(b.z); r[7] = (short)f2bf(b.w);
    return r;
}

// one wave's 16x16xK=1024 contribution; xrow/wrow pre-offset to lane position
__device__ __forceinline__ void mfma_tile(
    const float* __restrict__ xp, const float* __restrict__ wp,
    float* __restrict__ dst, int dstr, int n0, int mh, int lane)
{
    f32x4 acc = {0.f, 0.f, 0.f, 0.f};
#pragma unroll 4
    for (int s = 0; s < 32; ++s) {
        float4 xa = *(const float4*)(xp + s * 32);
        float4 xb = *(const float4*)(xp + s * 32 + 4);
        float4 wa = *(const float4*)(wp + s * 32);
        float4 wb = *(const float4*)(wp + s * 32 + 4);
        acc = __builtin_amdgcn_mfma_f32_16x16x32_bf16(
            cvt8(xa, xb), cvt8(wa, wb), acc, 0, 0, 0);
    }
    int ccol = n0 + (lane & 15);
    int rbase = mh * 16 + ((lane >> 4) << 2);
    atomicAdd(dst + (size_t)(rbase + 0) * dstr + ccol, acc[0]);
    atomicAdd(dst + (size_t)(rbase + 1) * dstr + ccol, acc[1]);
    atomicAdd(dst + (size_t)(rbase + 2) * dstr + ccol, acc[2]);
    atomicAdd(dst + (size_t)(rbase + 3) * dstr + ccol, acc[3]);
}

// grid = 768 blocks x 256 thr = 3072 waves = 384 ntiles x 2 m-halves x 4 splits
__global__ __launch_bounds__(256) void qkv_mfma(
    const float* __restrict__ x, const float* __restrict__ wq,
    const float* __restrict__ wk, const float* __restrict__ wv,
    float* __restrict__ qb, float* __restrict__ knb, float* __restrict__ vnb)
{
    int gw = (blockIdx.x << 2) + (threadIdx.x >> 6);
    int lane = threadIdx.x & 63;
    int split = gw & 3;
    int mh = (gw >> 2) & 1;
    int nt = gw >> 3;
    const float* w; float* dst; int dstr; int n0;
    if (nt < 256)      { w = wq; n0 = nt * 16;         dst = qb;  dstr = 4096; }
    else if (nt < 320) { w = wk; n0 = (nt - 256) * 16; dst = knb; dstr = 1024; }
    else               { w = wv; n0 = (nt - 320) * 16; dst = vnb; dstr = 1024; }
    int row = lane & 15, kq = (lane >> 4) << 3;
    int kbase = split << 10;
    const float* xp = x + (size_t)(mh * 16 + row) * 4096 + kbase + kq;
    const float* wp = w + (size_t)(n0 + row) * 4096 + kbase + kq;
    mfma_tile(xp, wp, dst, dstr, n0, mh, lane);
}

// grid = 512 blocks x 256 thr = 2048 waves = 256 ntiles x 2 m-halves x 4 splits
__global__ __launch_bounds__(256) void wo_mfma(
    const float* __restrict__ attn, const float* __restrict__ wo,
    float* __restrict__ out)
{
    int gw = (blockIdx.x << 2) + (threadIdx.x >> 6);
    int lane = threadIdx.x & 63;
    int split = gw & 3;
    int mh = (gw >> 2) & 1;
    int nt = gw >> 3;
    int n0 = nt * 16;
    int row = lane & 15, kq = (lane >> 4) << 3;
    int kbase = split << 10;
    const float* xp = attn + (size_t)(mh * 16 + row) * 4096 + kbase + kq;
    const float* wp = wo + (size_t)(n0 + row) * 4096 + kbase + kq;
    mfma_tile(xp, wp, out, 4096, n0, mh, lane);
}

// ---------------------------------------------------------------------------
// RoPE in-place on q (32 heads) and k_new (8 heads). grid = 32*40, block = 64.
// ---------------------------------------------------------------------------
__global__ void rope_kernel(float* __restrict__ qb, float* __restrict__ knb,
                            const int* __restrict__ lens)
{
    int bid = blockIdx.x;
    int b = bid / 40, r = bid % 40;
    float* row = (r < 32) ? (qb + (size_t)b * 4096 + r * 128)
                          : (knb + (size_t)b * 1024 + (r - 32) * 128);
    int d = threadIdx.x;
    float pos = (float)(lens[b] - 1);
    float inv = exp2f(-(float)d * 0.207620505930460f);  // 10000^(-d/64)
    float fr = pos * inv;
    float s, c;
    sincosf(fr, &s, &c);
    float x1 = row[d], x2 = row[d + 64];
    row[d]      = x1 * c - x2 * s;
    row[d + 64] = x2 * c + x1 * s;
}

// ---------------------------------------------------------------------------
// Flash-decode attention v3 (R10, best measured). One wave per (b, kv-head,
// 128-chunk). Subgroup-local online softmax; 3-deep named-reg K/V prefetch;
// zero barriers, zero K/V LDS. (v4 full-row streaming regressed +21us; v3 is
// the keeper.) All staging regs named scalars (rule #20).
// ---------------------------------------------------------------------------
#define MUL4(V, S) { V.x *= S; V.y *= S; V.z *= S; V.w *= S; }
#define FMA4(O, P, V) { O.x = fmaf(P, V.x, O.x); O.y = fmaf(P, V.y, O.y); \
                        O.z = fmaf(P, V.z, O.z); O.w = fmaf(P, V.w, O.w); }
#define DOT8(S, QA, QB, K0, K1) { \
    S = fmaf(QA.x, K0.x, S); S = fmaf(QA.y, K0.y, S); \
    S = fmaf(QA.z, K0.z, S); S = fmaf(QA.w, K0.w, S); \
    S = fmaf(QB.x, K1.x, S); S = fmaf(QB.y, K1.y, S); \
    S = fmaf(QB.z, K1.z, S); S = fmaf(QB.w, K1.w, S); }
#define RED16(X) { X += __shfl_xor(X, 1, 64); X += __shfl_xor(X, 2, 64); \
                   X += __shfl_xor(X, 4, 64); X += __shfl_xor(X, 8, 64); }
#define REDG_SUM(X) { X += __shfl_xor(X, 16, 64); X += __shfl_xor(X, 32, 64); }
#define REDG_MAX(X) { X = fmaxf(X, __shfl_xor(X, 16, 64)); \
                      X = fmaxf(X, __shfl_xor(X, 32, 64)); }
#define REDG_SUM4(V) { REDG_SUM(V.x) REDG_SUM(V.y) REDG_SUM(V.z) REDG_SUM(V.w) }

#define ALOADR(S, r_) { \
    int sl = ss[((r_) << 2) + g]; \
    const float* kp; const float* vp; \
    if (sl < 0) { kp = knew; vp = vnew; } \
    else { kp = kc + (size_t)sl * 1024 + hoff; vp = vc + (size_t)sl * 1024 + hoff; } \
    S##k0 = *(const float4*)(kp + isl); S##k1 = *(const float4*)(kp + isl + 4); \
    S##v0 = *(const float4*)(vp + isl); S##v1 = *(const float4*)(vp + isl + 4); }

#define OUPD(s_, m_, l_, Oa_, Ob_, V0_, V1_, vld_) { \
    if (s_ > m_) { \
        float c_ = __expf(m_ - s_); \
        l_ *= c_; MUL4(Oa_, c_) MUL4(Ob_, c_) \
        m_ = s_; \
    } \
    float pe_ = vld_ ? __expf(s_ - m_) : 0.f; \
    l_ += pe_; \
    FMA4(Oa_, pe_, V0_) FMA4(Ob_, pe_, V1_) }

#define ACOMP(S, r_) { \
    float s0 = 0.f, s1 = 0.f, s2 = 0.f, s3 = 0.f; \
    DOT8(s0, q0a, q0b, S##k0, S##k1) \
    DOT8(s1, q1a, q1b, S##k0, S##k1) \
    DOT8(s2, q2a, q2b, S##k0, S##k1) \
    DOT8(s3, q3a, q3b, S##k0, S##k1) \
    RED16(s0) RED16(s1) RED16(s2) RED16(s3) \
    int vld = (((r_) << 2) + g) < pend; \
    if (!vld) { s0 = s1 = s2 = s3 = -INFINITY; } \
    OUPD(s0, m0, l0, o0a, o0b, S##v0, S##v1, vld) \
    OUPD(s1, m1, l1, o1a, o1b, S##v0, S##v1, vld) \
    OUPD(s2, m2, l2, o2a, o2b, S##v0, S##v1, vld) \
    OUPD(s3, m3, l3, o3a, o3b, S##v0, S##v1, vld) }

__global__ __launch_bounds__(64, 1) void attn_kernel(
    const float* __restrict__ kc, const float* __restrict__ vc,
    const float* __restrict__ qb, const float* __restrict__ knb,
    const float* __restrict__ vnb,
    const int* __restrict__ btab, const int* __restrict__ lens,
    float* __restrict__ part)
{
    int bid = blockIdx.x;
    int c = bid & 15, h = (bid >> 4) & 7, b = bid >> 7;
    int len = lens[b];
    int p0 = c << 7;
    if (p0 >= len) return;
    int pend = min(len - p0, 128);
    int nr = (pend + 3) >> 2;     // rounds of 4 positions
    int last = len - 1;

    __shared__ int ss[128];       // slot table; -1 => new k/v row (wave-private)

    int lane = threadIdx.x;
    int g = lane >> 4;            // position-in-round 0..3
    int isl = (lane & 15) << 3;   // dim slice base 0,8,...,120
    int hoff = h * 128;

    {   // slot table: each lane fills 2 consecutive entries (same btab word)
        int idx = lane << 1;
        int p = p0 + idx;
        int bt = btab[b * 128 + (p >> 4)];
        int base = bt * 16 + (p & 15);
        ss[idx]     = (p     == last) ? -1 : base;
        ss[idx + 1] = (p + 1 == last) ? -1 : base + 1;
    }

    const float* knew = knb + ((size_t)b * 8 + h) * 128;
    const float* vnew = vnb + ((size_t)b * 8 + h) * 128;

    const float scale = 0.08838834764831845f;   // 1/sqrt(128)
    const float* qrow = qb + (size_t)b * 4096 + (size_t)h * 512;
    float4 q0a = *(const float4*)(qrow + isl),       q0b = *(const float4*)(qrow + isl + 4);
    float4 q1a = *(const float4*)(qrow + 128 + isl), q1b = *(const float4*)(qrow + 128 + isl + 4);
    float4 q2a = *(const float4*)(qrow + 256 + isl), q2b = *(const float4*)(qrow + 256 + isl + 4);
    float4 q3a = *(const float4*)(qrow + 384 + isl), q3b = *(const float4*)(qrow + 384 + isl + 4);
    MUL4(q0a, scale) MUL4(q0b, scale) MUL4(q1a, scale) MUL4(q1b, scale)
    MUL4(q2a, scale) MUL4(q2b, scale) MUL4(q3a, scale) MUL4(q3b, scale)

    float m0 = -INFINITY, m1 = -INFINITY, m2 = -INFINITY, m3 = -INFINITY;
    float l0 = 0.f, l1 = 0.f, l2 = 0.f, l3 = 0.f;
    float4 o0a = {0,0,0,0}, o0b = {0,0,0,0}, o1a = {0,0,0,0}, o1b = {0,0,0,0};
    float4 o2a = {0,0,0,0}, o2b = {0,0,0,0}, o3a = {0,0,0,0}, o3b = {0,0,0,0};

    float4 ak0, ak1, av0, av1;
    float4 bk0, bk1, bv0, bv1;
    float4 ck0, ck1, cv0, cv1;
    ALOADR(a, 0)
    if (1 < nr) ALOADR(b, 1)
    if (2 < nr) ALOADR(c, 2)
    for (int r = 0; r < nr; r += 3) {
        ACOMP(a, r)
        if (r + 3 < nr) ALOADR(a, r + 3)
        if (r + 1 >= nr) break;
        ACOMP(b, r + 1)
        if (r + 4 < nr) ALOADR(b, r + 4)
        if (r + 2 >= nr) break;
        ACOMP(c, r + 2)
        if (r + 5 < nr) ALOADR(c, r + 5)
    }

    // merge the 4 subgroup partial softmaxes (once per wave)
    float M0 = m0, M1 = m1, M2 = m2, M3 = m3;
    REDG_MAX(M0) REDG_MAX(M1) REDG_MAX(M2) REDG_MAX(M3)
    float w0 = __expf(m0 - M0), w1 = __expf(m1 - M1);
    float w2 = __expf(m2 - M2), w3 = __expf(m3 - M3);
    float L0 = w0 * l0, L1 = w1 * l1, L2 = w2 * l2, L3 = w3 * l3;
    REDG_SUM(L0) REDG_SUM(L1) REDG_SUM(L2) REDG_SUM(L3)
    MUL4(o0a, w0) MUL4(o0b, w0) MUL4(o1a, w1) MUL4(o1b, w1)
    MUL4(o2a, w2) MUL4(o2b, w2) MUL4(o3a, w3) MUL4(o3b, w3)
    REDG_SUM4(o0a) REDG_SUM4(o0b) REDG_SUM4(o1a) REDG_SUM4(o1b)
    REDG_SUM4(o2a) REDG_SUM4(o2b) REDG_SUM4(o3a) REDG_SUM4(o3b)

    // partial layout: per (b,h,c): 4 heads x 132 floats [O[128], m, l, pad2]
    float* pgb = part + (size_t)(((b * 8 + h) * 16 + c) * 4) * 132;
    if (lane < 16) {
        *(float4*)(pgb +       isl) = o0a; *(float4*)(pgb +       isl + 4) = o0b;
        *(float4*)(pgb + 132 + isl) = o1a; *(float4*)(pgb + 132 + isl + 4) = o1b;
        *(float4*)(pgb + 264 + isl) = o2a; *(float4*)(pgb + 264 + isl + 4) = o2b;
        *(float4*)(pgb + 396 + isl) = o3a; *(float4*)(pgb + 396 + isl + 4) = o3b;
    }
    if (lane == 0) {
        pgb[128] = M0; pgb[129] = L0;
        pgb[260] = M1; pgb[261] = L1;
        pgb[392] = M2; pgb[393] = L2;
        pgb[524] = M3; pgb[525] = L3;
    }
}

// grid = 256 (b*8+h), block = 256 (4 heads x 64 lanes)
__global__ __launch_bounds__(256) void combine_kernel(
    const float* __restrict__ part, const int* __restrict__ lens,
    float* __restrict__ attn)
{
    int b = blockIdx.x >> 3, h = blockIdx.x & 7;
    int t = threadIdx.x;
    int g = t >> 6, lane = t & 63;
    int len = lens[b];
    int nch = (len + 127) >> 7;
    const float* base = part + (size_t)(b * 8 + h) * 8448 + (size_t)g * 132;
    float M = -INFINITY;
    for (int cc = 0; cc < nch; ++cc)
        M = fmaxf(M, base[(size_t)cc * 528 + 128]);
    float denom = 0.f, a0 = 0.f, a1 = 0.f;
    int d0 = lane << 1;
    for (int cc = 0; cc < nch; ++cc) {
        const float* pg = base + (size_t)cc * 528;
        float w = __expf(pg[128] - M);
        denom += w * pg[129];
        a0 += w * pg[d0];
        a1 += w * pg[d0 + 1];
    }
    float inv = 1.f / denom;
    float* dst = attn + (size_t)b * 4096 + (size_t)(h * 4 + g) * 128 + d0;
    dst[0] = a0 * inv;
    dst[1] = a1 * inv;
}

// ---------------------------------------------------------------------------
// Workspace (floats): qb[32][4096] @0, knb[32*1024] @131072, vnb @163840,
// attn[32][4096] @196608, part[32*8*16*4*132] @327680 (~8.7MB; total ~10MB)
// ---------------------------------------------------------------------------
extern "C" void kernel_launch(void* const* d_in, const int* in_sizes, int n_in,
                              void* d_out, int out_size, void* d_ws, size_t ws_size,
                              hipStream_t stream)
{
    const float* x   = (const float*)d_in[0];
    const float* wq  = (const float*)d_in[1];
    const float* wk  = (const float*)d_in[2];
    const float* wv  = (const float*)d_in[3];
    const float* wo  = (const float*)d_in[4];
    const float* kc  = (const float*)d_in[5];
    const float* vc  = (const float*)d_in[6];
    const int* btab  = (const int*)d_in[8];
    const int* lens  = (const int*)d_in[10];

    float* qb   = (float*)d_ws;
    float* knb  = qb  + 32 * 4096;
    float* vnb  = knb + 32 * 1024;
    float* attn = vnb + 32 * 1024;
    float* part = attn + 32 * 4096;
    float* outp = (float*)d_out;

    hipMemsetAsync(d_ws, 0, (size_t)(32 * 4096 + 2 * 32 * 1024) * sizeof(float), stream);
    hipMemsetAsync(d_out, 0, (size_t)32 * 4096 * sizeof(float), stream);

    qkv_mfma<<<768, 256, 0, stream>>>(x, wq, wk, wv, qb, knb, vnb);
    rope_kernel<<<32 * 40, 64, 0, stream>>>(qb, knb, lens);
    attn_kernel<<<4096, 64, 0, stream>>>(kc, vc, qb, knb, vnb, btab, lens, part);
    combine_kernel<<<256, 256, 0, stream>>>(part, lens, attn);
    wo_mfma<<<512, 256, 0, stream>>>(attn, wo, outp);
}